// Round 13
// baseline (281.725 us; speedup 1.0000x reference)
//
#include <hip/hip_runtime.h>

// ---------------------------------------------------------------------------
// LinearSelfAttention: B=4 T=4096 DIM=1024 H=16 E=64 BUCKET=64 U=64
// ---------------------------------------------------------------------------

#define T_LEN 4096
#define DIMN  1024
#define NHEAD 16
#define NB    4
#define MROWS (NB * T_LEN)   // 16384

typedef float f32x4 __attribute__((ext_vector_type(4)));
typedef float f32x16 __attribute__((ext_vector_type(16)));
typedef short s16x8 __attribute__((ext_vector_type(8)));
typedef short s16x4 __attribute__((ext_vector_type(4)));
using u16 = unsigned short;

__device__ __forceinline__ u16 f2bf(float f) {
  unsigned int u = __float_as_uint(f);
  u += 0x7fffu + ((u >> 16) & 1u);   // RNE
  return (u16)(u >> 16);
}
__device__ __forceinline__ float bf2f(u16 h) {
  return __uint_as_float(((unsigned int)h) << 16);
}

// ------------------- fused weight transpose+cast AND x cast ----------------
__global__ __launch_bounds__(256) void cvt_all_kern(const float* __restrict__ x,
                                                    const float* __restrict__ W0,
                                                    const float* __restrict__ W1,
                                                    const float* __restrict__ W2,
                                                    const float* __restrict__ W3,
                                                    u16* __restrict__ WT,
                                                    u16* __restrict__ xb) {
  __shared__ float tile[64][65];
  const int tid = threadIdx.x;
  if (blockIdx.x < 1024) {
    const int blk = blockIdx.x & 255;
    const int sel = blockIdx.x >> 8;
    const float* W = (sel == 0) ? W0 : (sel == 1) ? W1 : (sel == 2) ? W2 : W3;
    u16* dst = WT + (size_t)sel * DIMN * DIMN;
    const int k0 = (blk >> 4) << 6;
    const int n0 = (blk & 15) << 6;
    const int r = tid >> 6;
    const int c = tid & 63;
#pragma unroll
    for (int i = 0; i < 16; ++i) {
      int row = (i << 2) + r;
      tile[row][c] = W[(size_t)(k0 + row) * DIMN + n0 + c];
    }
    __syncthreads();
#pragma unroll
    for (int i = 0; i < 16; ++i) {
      int row = (i << 2) + r;
      dst[(size_t)(n0 + row) * DIMN + k0 + c] = f2bf(tile[c][row]);
    }
  } else {
    size_t i = ((size_t)(blockIdx.x - 1024) * 256 + tid) * 4;
    f32x4 v = *(const f32x4*)(x + i);
    s16x4 o;
    o.x = (short)f2bf(v.x); o.y = (short)f2bf(v.y);
    o.z = (short)f2bf(v.z); o.w = (short)f2bf(v.w);
    *(s16x4*)(xb + i) = o;
  }
}

// ------------- 128x256 triple-buffered 32x32x16-MFMA bf16 GEMM --------------
// MODE 0: N=3072 fused QKV -> q (softmax64, [n][dim]), k (elu+1 -> kT[bh][d][t]),
//         v (-> vT[bh][d][t])  — k/v epilogue staged through LDS (coalesced)
// MODE 1: N=1024 -> f32 out + bias (direct stores)
// 512 thr = 8 waves (2Mx4N); per-wave 64x64 = 2x2 of 32x32; BK=32 (kk 2xK16).
// LDS 72KB: 3 buf x [A 8K | B 16K]; counted vmcnt(3), depth-2 (R9 protocol).
// Slot swizzle for 32-row reads: slot = (chunk + (row>>1)) & 3  -> 2-way (free).
// Write side pre-swizzles SOURCE col (linear LDS dest, rule #21).
// C/D layout (HW-verified): col = lane&31, row = (r&3)+8*(r>>2)+4*(lane>>5).
template <int MODE>
__global__ __launch_bounds__(512, 4) void gemm_t(
    const u16* __restrict__ A, const u16* __restrict__ Bt,
    u16* __restrict__ dq, u16* __restrict__ dk, u16* __restrict__ dv,
    float* __restrict__ dO, const float* __restrict__ bias) {
  constexpr int K = 1024;
  constexpr int BNT = (MODE == 0) ? 12 : 4;   // N / 256
  constexpr int NT = K / 32;                  // 32 K-steps
  __shared__ char lds[73728];                 // 3 x 24576; reused by epilogue

  const int tid = threadIdx.x;
  const int l = tid & 63;
  const int w = tid >> 6;
  const int wm = w >> 2;           // 0..1 (64 rows each)
  const int wn = w & 3;            // 0..3 (64 cols each)
  const int l31 = l & 31;
  const int lh = l >> 5;           // 0..1

  const int xcd = (int)blockIdx.x & 7;
  const int idx = (int)blockIdx.x >> 3;
  const int g = idx / (4 * BNT);
  const int r2 = idx % (4 * BNT);
  const int bn = r2 >> 2;
  const int bm = xcd * 16 + g * 4 + (r2 & 3);
  const size_t arow0 = (size_t)bm * 128;
  const size_t brow0 = (size_t)bn * 256;

  // staging decode: phys chunk ch (16B) -> row = ch>>2, slot s = ch&3;
  // logical k-chunk = (s - ((row>>1)&3)) & 3 -> source col offset (bf16)
  const int arow_s = tid >> 2;
  const int acol_s = ((((tid & 3) - ((arow_s >> 1) & 3)) & 3)) * 8;
  int brow_s[2], bcol_s[2];
#pragma unroll
  for (int i = 0; i < 2; ++i) {
    const int ch = i * 512 + tid;
    brow_s[i] = ch >> 2;
    bcol_s[i] = ((((ch & 3) - ((brow_s[i] >> 1) & 3)) & 3)) * 8;
  }

  auto STAGE = [&](int buf, int matsel, int tt) {
    const int kbase = (tt & (NT - 1)) * 32;
#pragma unroll
    for (int i = 0; i < 2; ++i) {
      if (matsel == 0 && i == 1) break;
      const u16* src = (matsel == 0)
          ? A  + (arow0 + (size_t)arow_s) * K + kbase + acol_s
          : Bt + (brow0 + (size_t)brow_s[i]) * K + kbase + bcol_s[i];
      char* dst = lds + (buf * 24576 + matsel * 8192 + (i * 512 + tid) * 16);
      __builtin_amdgcn_global_load_lds(
          (__attribute__((address_space(1))) const void*)src,
          (__attribute__((address_space(3))) void*)dst, 16, 0, 0);
    }
  };
  // fragment read: row = block-local row, ck = kk*2 + lh
  auto LDA32 = [&](int buf, int mb, int kk) -> s16x8 {
    const int row = wm * 64 + mb * 32 + l31;
    const int slot = ((kk * 2 + lh) + ((row >> 1) & 3)) & 3;
    return *(const s16x8*)(lds + buf * 24576 + row * 64 + slot * 16);
  };
  auto LDB32 = [&](int buf, int nb, int kk) -> s16x8 {
    const int row = wn * 64 + nb * 32 + l31;
    const int slot = ((kk * 2 + lh) + ((row >> 1) & 3)) & 3;
    return *(const s16x8*)(lds + buf * 24576 + 8192 + row * 64 + slot * 16);
  };

  f32x16 acc[2][2];
#pragma unroll
  for (int i = 0; i < 2; ++i)
#pragma unroll
    for (int j = 0; j < 2; ++j)
#pragma unroll
      for (int e = 0; e < 16; ++e) acc[i][j][e] = 0.f;

  STAGE(0, 0, 0); STAGE(0, 1, 0);
  STAGE(1, 0, 1); STAGE(1, 1, 1);
  asm volatile("s_waitcnt vmcnt(3)" ::: "memory");
  __builtin_amdgcn_sched_barrier(0);
  __builtin_amdgcn_s_barrier();

  s16x8 af[2][2], bfr[2][2];

  int bufR = 0, bufW = 2;
#pragma unroll 1
  for (int t = 0; t < NT; ++t) {
    STAGE(bufW, 0, t + 2);
    STAGE(bufW, 1, t + 2);
#pragma unroll
    for (int kk = 0; kk < 2; ++kk) {
#pragma unroll
      for (int mb = 0; mb < 2; ++mb) af[mb][kk] = LDA32(bufR, mb, kk);
#pragma unroll
      for (int nb = 0; nb < 2; ++nb) bfr[nb][kk] = LDB32(bufR, nb, kk);
    }
    __builtin_amdgcn_s_setprio(1);
#pragma unroll
    for (int mb = 0; mb < 2; ++mb)
#pragma unroll
      for (int nb = 0; nb < 2; ++nb)
#pragma unroll
        for (int kk = 0; kk < 2; ++kk)
          acc[mb][nb] = __builtin_amdgcn_mfma_f32_32x32x16_bf16(
              af[mb][kk], bfr[nb][kk], acc[mb][nb], 0, 0, 0);
    __builtin_amdgcn_s_setprio(0);
    asm volatile("s_waitcnt vmcnt(3)" ::: "memory");
    __builtin_amdgcn_sched_barrier(0);
    __builtin_amdgcn_s_barrier();
    bufR = (bufR == 2) ? 0 : bufR + 1;
    bufW = (bufW == 2) ? 0 : bufW + 1;
  }

  // drain all in-flight staging before any LDS reuse
  asm volatile("s_waitcnt vmcnt(0) lgkmcnt(0)" ::: "memory");
  __builtin_amdgcn_sched_barrier(0);
  __builtin_amdgcn_s_barrier();

  // ---- epilogue: D row = (r&3)+8*(r>>2)+4*lh, col = l31 (within 32x32) ----
  if constexpr (MODE == 0) {
    const int mat = bn >> 2;                        // 0=q 1=k 2=v
    if (mat == 0) {
      u16* dst = dq;
      const size_t colbase = (size_t)(bn & 3) * 256 + (size_t)wn * 64;
      // per-head softmax: head = wave's 64 cols = nb0|nb1; rows live in one
      // 32-lane half -> shfl_xor 1..16 stays within the half.
#pragma unroll
      for (int mb = 0; mb < 2; ++mb) {
#pragma unroll
        for (int r = 0; r < 16; ++r) {
          float v0 = acc[mb][0][r], v1 = acc[mb][1][r];
          float m = fmaxf(v0, v1);
#pragma unroll
          for (int off = 1; off < 32; off <<= 1) m = fmaxf(m, __shfl_xor(m, off));
          float e0 = __expf(v0 - m), e1 = __expf(v1 - m);
          float s = e0 + e1;
#pragma unroll
          for (int off = 1; off < 32; off <<= 1) s += __shfl_xor(s, off);
          float inv = 1.f / s;
          const int rl = (r & 3) + 8 * (r >> 2) + 4 * lh;
          const size_t row = arow0 + wm * 64 + mb * 32 + rl;
          u16* p = dst + row * DIMN + colbase + l31;
          p[0]  = f2bf(e0 * inv);
          p[32] = f2bf(e1 * inv);
        }
      }
    } else {
      // k/v: stage C-tile in LDS as [col 256][t 132-pad], then coalesced
      // stores along t into kT/vT [bh][d][t].  t-consecutive via r=4a..4a+3.
      u16* dst = (mat == 1) ? dk : dv;
      u16* lt = (u16*)lds;
#pragma unroll
      for (int mb = 0; mb < 2; ++mb) {
#pragma unroll
        for (int nb = 0; nb < 2; ++nb) {
          const int cl = wn * 64 + nb * 32 + l31;
#pragma unroll
          for (int a = 0; a < 4; ++a) {
            const int tl = wm * 64 + mb * 32 + 8 * a + 4 * lh;
            s16x4 o;
#pragma unroll
            for (int j = 0; j < 4; ++j) {
              float v = acc[mb][nb][a * 4 + j];
              float r = (mat == 1) ? (v > 0.f ? v + 1.f : __expf(v)) : v;
              o[j] = (short)f2bf(r);
            }
            *(s16x4*)&lt[cl * 132 + tl] = o;
          }
        }
      }
      __builtin_amdgcn_s_barrier();
      const int colb = (bn & 3) * 256;
      const int bb = (int)(arow0 >> 12);
      const int t0 = (int)(arow0 & 4095);
#pragma unroll
      for (int i = 0; i < 8; ++i) {
        const int chunk = i * 512 + tid;          // 4096 chunks
        const int cl = chunk >> 4;                // 0..255
        const int toct = (chunk & 15) * 8;
        s16x8 vv = *(const s16x8*)&lt[cl * 132 + toct];
        const int col = colb + cl;
        const int h = col >> 6, d = col & 63;
        *(s16x8*)&dst[((size_t)((bb * 16 + h) * 64 + d)) * 4096 + t0 + toct] = vv;
      }
    }
  } else {
#pragma unroll
    for (int mb = 0; mb < 2; ++mb)
#pragma unroll
      for (int nb = 0; nb < 2; ++nb) {
        const size_t col = brow0 + (size_t)wn * 64 + nb * 32 + l31;
        const float bv = bias[col];
#pragma unroll
        for (int r = 0; r < 16; ++r) {
          const int rl = (r & 3) + 8 * (r >> 2) + 4 * lh;
          const size_t row = arow0 + wm * 64 + mb * 32 + rl;
          dO[row * DIMN + col] = acc[mb][nb][r] + bv;
        }
      }
  }
}

// -------------------- fused middle v2: producer/consumer waves --------------
// (unchanged from R12 — verified)
__global__ __launch_bounds__(512) void mid_fused_kern(const u16* __restrict__ kT,
                                                      const u16* __restrict__ vT,
                                                      const u16* __restrict__ qb,
                                                      u16* __restrict__ attn) {
  __shared__ u16 cprev[2][16][72];   // bf16 [e][d], 144B rows (16B-aligned)
  const int tid = threadIdx.x;
  const int l = tid & 63;
  const int w = tid >> 6;           // 0..7
  const int ws = w & 3;
  const bool isCtx = w < 4;
  const int fr = l & 15;
  const int lg = l >> 4;            // 0..3

  const int bid = (int)blockIdx.x;
  const int xcd = bid & 7;
  const int slot = bid >> 3;        // 0..31
  const int bh = xcd * 8 + (slot >> 2);
  const int eg = slot & 3;
  const int b = bh >> 4, h = bh & 15;

  const size_t kvbase = (size_t)bh * 64 * 4096;   // [d][t]
  const size_t qrow0 = (size_t)b * T_LEN;

  if (isCtx) {
#pragma unroll
    for (int j = 0; j < 4; ++j) cprev[0][lg * 4 + j][ws * 16 + fr] = 0;
  }
  __syncthreads();

  if (isCtx) {
    auto LV = [&](int u, int kk) -> s16x8 {   // vT rows e (A operand)
      return *(const s16x8*)&vT[kvbase + (size_t)(eg * 16 + fr) * 4096 +
                                u * 64 + kk * 32 + lg * 8];
    };
    auto LK = [&](int u, int kk) -> s16x8 {   // kT rows d (B operand)
      return *(const s16x8*)&kT[kvbase + (size_t)(ws * 16 + fr) * 4096 +
                                u * 64 + kk * 32 + lg * 8];
    };
    f32x4 cacc = {0.f, 0.f, 0.f, 0.f};   // rows e=lg*4+j, col d=ws*16+fr
    float ksum = 0.f;
    s16x8 vA0 = LV(0, 0), vA1 = LV(0, 1);
    s16x8 kB0 = LK(0, 0), kB1 = LK(0, 1);
#pragma unroll 1
    for (int u = 0; u < 64; ++u) {
      const s16x8 cvA0 = vA0, cvA1 = vA1, ckB0 = kB0, ckB1 = kB1;
      if (u < 63) {
        vA0 = LV(u + 1, 0); vA1 = LV(u + 1, 1);
        kB0 = LK(u + 1, 0); kB1 = LK(u + 1, 1);
      }
      cacc = __builtin_amdgcn_mfma_f32_16x16x32_bf16(cvA0, ckB0, cacc, 0, 0, 0);
      cacc = __builtin_amdgcn_mfma_f32_16x16x32_bf16(cvA1, ckB1, cacc, 0, 0, 0);
      float s = 0.f;
#pragma unroll
      for (int j = 0; j < 8; ++j)
        s += bf2f((u16)ckB0[j]) + bf2f((u16)ckB1[j]);
      s += __shfl_xor(s, 16);
      s += __shfl_xor(s, 32);
      ksum += s;
      const float inv = 1.f / (ksum + 1e-6f);
      u16* pp = &cprev[(u + 1) & 1][lg * 4][ws * 16 + fr];
#pragma unroll
      for (int j = 0; j < 4; ++j) pp[j * 72] = f2bf(cacc[j] * inv);
      __syncthreads();
    }
  } else {
    auto LQ = [&](int u, int kk) -> s16x8 {   // q rows n (A operand)
      return *(const s16x8*)&qb[(qrow0 + u * 64 + ws * 16 + fr) * DIMN +
                                (size_t)h * 64 + kk * 32 + lg * 8];
    };
    s16x8 qA0 = LQ(0, 0), qA1 = LQ(0, 1);
#pragma unroll 1
    for (int u = 0; u < 64; ++u) {
      const s16x8 cqA0 = qA0, cqA1 = qA1;
      if (u < 63) { qA0 = LQ(u + 1, 0); qA1 = LQ(u + 1, 1); }
      s16x8 cB0 = *(const s16x8*)&cprev[u & 1][fr][lg * 8];
      s16x8 cB1 = *(const s16x8*)&cprev[u & 1][fr][32 + lg * 8];
      f32x4 aacc = {0.f, 0.f, 0.f, 0.f};
      aacc = __builtin_amdgcn_mfma_f32_16x16x32_bf16(cqA0, cB0, aacc, 0, 0, 0);
      aacc = __builtin_amdgcn_mfma_f32_16x16x32_bf16(cqA1, cB1, aacc, 0, 0, 0);
      const size_t arow = qrow0 + (size_t)u * 64 + ws * 16 + lg * 4;
#pragma unroll
      for (int j = 0; j < 4; ++j)
        attn[(arow + j) * DIMN + (size_t)h * 64 + eg * 16 + fr] = f2bf(aacc[j]);
      __syncthreads();
    }
  }
}

// ---------------------------------------------------------------------------
extern "C" void kernel_launch(void* const* d_in, const int* in_sizes, int n_in,
                              void* d_out, int out_size, void* d_ws, size_t ws_size,
                              hipStream_t stream) {
  const float* x  = (const float*)d_in[0];
  const float* Wq = (const float*)d_in[1];
  const float* Wk = (const float*)d_in[2];
  const float* Wv = (const float*)d_in[3];
  const float* Wo = (const float*)d_in[4];
  const float* bo = (const float*)d_in[5];
  float* out = (float*)d_out;

  constexpr size_t SZ_XB = (size_t)MROWS * DIMN * 2;
  constexpr size_t SZ_WT = (size_t)DIMN * DIMN * 2;
  char* ws = (char*)d_ws;
  u16*   xb   = (u16*)(ws);
  u16*   wqT  = (u16*)(ws + SZ_XB);          // wq/wk/wv/wo contiguous
  u16*   woT  = (u16*)(ws + SZ_XB + 3 * SZ_WT);
  u16*   qb   = (u16*)(ws + SZ_XB + 4 * SZ_WT);
  u16*   kT   = (u16*)(ws + 2 * SZ_XB + 4 * SZ_WT);   // [bh][d][t]
  u16*   vT   = (u16*)(ws + 3 * SZ_XB + 4 * SZ_WT);   // [bh][d][t]
  u16*   attn = xb;  // xb dead after QKV GEMM

  cvt_all_kern<<<1024 + MROWS * DIMN / 1024, 256, 0, stream>>>(x, Wq, Wk, Wv, Wo,
                                                               wqT, xb);

  // fused QKV: N = 3072, grid 128 x 12 = 1536
  gemm_t<0><<<1536, 512, 0, stream>>>(xb, wqT, qb, kT, vT, nullptr, nullptr);

  // fused middle: ctx + cumnorm + attn, one pass, producer/consumer waves
  mid_fused_kern<<<256, 512, 0, stream>>>(kT, vT, qb, attn);

  // output: N = 1024, grid 128 x 4 = 512
  gemm_t<1><<<512, 512, 0, stream>>>(attn, woT, nullptr, nullptr, nullptr, out, bo);
}

// Round 14
// 245.233 us; speedup vs baseline: 1.1488x; 1.1488x over previous
//
#include <hip/hip_runtime.h>

// ---------------------------------------------------------------------------
// LinearSelfAttention: B=4 T=4096 DIM=1024 H=16 E=64 BUCKET=64 U=64
// ---------------------------------------------------------------------------

#define T_LEN 4096
#define DIMN  1024
#define NHEAD 16
#define NB    4
#define MROWS (NB * T_LEN)   // 16384

typedef float f32x4 __attribute__((ext_vector_type(4)));
typedef short s16x8 __attribute__((ext_vector_type(8)));
typedef short s16x4 __attribute__((ext_vector_type(4)));
using u16 = unsigned short;

__device__ __forceinline__ u16 f2bf(float f) {
  unsigned int u = __float_as_uint(f);
  u += 0x7fffu + ((u >> 16) & 1u);   // RNE
  return (u16)(u >> 16);
}
__device__ __forceinline__ float bf2f(u16 h) {
  return __uint_as_float(((unsigned int)h) << 16);
}
// involution swizzle within a slot ([rows][32 bf16] = row*64B); row-pair-local,
// so valid for any slot size (8K A, 16K/32K B).
__device__ __forceinline__ int swz16k(int off) {
  return off ^ (((off >> 7) & 3) << 4);
}

// ------------------- fused weight transpose+cast AND x cast ----------------
__global__ __launch_bounds__(256) void cvt_all_kern(const float* __restrict__ x,
                                                    const float* __restrict__ W0,
                                                    const float* __restrict__ W1,
                                                    const float* __restrict__ W2,
                                                    const float* __restrict__ W3,
                                                    u16* __restrict__ WT,
                                                    u16* __restrict__ xb) {
  __shared__ float tile[64][65];
  const int tid = threadIdx.x;
  if (blockIdx.x < 1024) {
    const int blk = blockIdx.x & 255;
    const int sel = blockIdx.x >> 8;
    const float* W = (sel == 0) ? W0 : (sel == 1) ? W1 : (sel == 2) ? W2 : W3;
    u16* dst = WT + (size_t)sel * DIMN * DIMN;
    const int k0 = (blk >> 4) << 6;
    const int n0 = (blk & 15) << 6;
    const int r = tid >> 6;
    const int c = tid & 63;
#pragma unroll
    for (int i = 0; i < 16; ++i) {
      int row = (i << 2) + r;
      tile[row][c] = W[(size_t)(k0 + row) * DIMN + n0 + c];
    }
    __syncthreads();
#pragma unroll
    for (int i = 0; i < 16; ++i) {
      int row = (i << 2) + r;
      dst[(size_t)(n0 + row) * DIMN + k0 + c] = f2bf(tile[c][row]);
    }
  } else {
    size_t i = ((size_t)(blockIdx.x - 1024) * 256 + tid) * 4;
    f32x4 v = *(const f32x4*)(x + i);
    s16x4 o;
    o.x = (short)f2bf(v.x); o.y = (short)f2bf(v.y);
    o.z = (short)f2bf(v.z); o.w = (short)f2bf(v.w);
    *(s16x4*)(xb + i) = o;
  }
}

// ------------- QKV: 128x256 triple-buffered counted-vmcnt bf16 GEMM ---------
// N=3072 fused -> q (softmax64, [n][dim]), k (elu+1 -> kT[bh][d][t]),
// v (-> vT[bh][d][t]); k/v epilogue staged through LDS (coalesced).
// R9/R12 core (verified): 8 waves 2Mx4N, BK=32, 3 LDS buffers, vmcnt(3).
__global__ __launch_bounds__(512, 4) void gemm_qkv(
    const u16* __restrict__ A, const u16* __restrict__ Bt,
    u16* __restrict__ dq, u16* __restrict__ dk, u16* __restrict__ dv) {
  constexpr int K = 1024;
  constexpr int BNT = 12;                     // N / 256
  constexpr int NT = K / 32;                  // 32 K-steps
  __shared__ char lds[73728];                 // 3 x 24576; reused by epilogue

  const int tid = threadIdx.x;
  const int l = tid & 63;
  const int w = tid >> 6;
  const int wm = w >> 2;           // 0..1 (64 rows each)
  const int wn = w & 3;            // 0..3 (64 cols each)

  const int xcd = (int)blockIdx.x & 7;
  const int idx = (int)blockIdx.x >> 3;
  const int g = idx / (4 * BNT);
  const int r2 = idx % (4 * BNT);
  const int bn = r2 >> 2;
  const int bm = xcd * 16 + g * 4 + (r2 & 3);
  const size_t arow0 = (size_t)bm * 128;
  const size_t brow0 = (size_t)bn * 256;

  int lrow[2], lcol[2];
#pragma unroll
  for (int i = 0; i < 2; ++i) {
    int lg2 = swz16k((i * 512 + tid) * 16);
    lrow[i] = lg2 >> 6;
    lcol[i] = (lg2 & 63) >> 1;
  }

  const int fr = l & 15;
  const int kswz = (((l >> 4) << 4)) ^ ((((fr >> 1) & 3)) << 4);

  auto STAGE = [&](int buf, int matsel, int tt) {
    const int kbase = (tt & (NT - 1)) * 32;
#pragma unroll
    for (int i = 0; i < 2; ++i) {
      if (matsel == 0 && i == 1) break;
      const u16* src = (matsel == 0)
          ? A  + (arow0 + (size_t)lrow[i]) * K + kbase + lcol[i]
          : Bt + (brow0 + (size_t)lrow[i]) * K + kbase + lcol[i];
      char* dst = lds + (buf * 24576 + matsel * 8192 + (i * 512 + tid) * 16);
      __builtin_amdgcn_global_load_lds(
          (__attribute__((address_space(1))) const void*)src,
          (__attribute__((address_space(3))) void*)dst, 16, 0, 0);
    }
  };
  auto LDA = [&](int buf, int rowb) -> s16x8 {
    return *(const s16x8*)(lds + buf * 24576 + rowb * 64 + kswz);
  };
  auto LDB = [&](int buf, int rowb) -> s16x8 {
    return *(const s16x8*)(lds + buf * 24576 + 8192 + rowb * 64 + kswz);
  };

  f32x4 acc[4][4];
#pragma unroll
  for (int i = 0; i < 4; ++i)
#pragma unroll
    for (int j = 0; j < 4; ++j) acc[i][j] = {0.f, 0.f, 0.f, 0.f};

  STAGE(0, 0, 0); STAGE(0, 1, 0);
  STAGE(1, 0, 1); STAGE(1, 1, 1);
  asm volatile("s_waitcnt vmcnt(3)" ::: "memory");
  __builtin_amdgcn_sched_barrier(0);
  __builtin_amdgcn_s_barrier();

  const int amb = wm * 64;
  const int bnb = wn * 64;
  s16x8 af[4], bf[4];

  int bufR = 0, bufW = 2;
#pragma unroll 1
  for (int t = 0; t < NT; ++t) {
    STAGE(bufW, 0, t + 2);
    STAGE(bufW, 1, t + 2);
#pragma unroll
    for (int i = 0; i < 4; ++i) af[i] = LDA(bufR, amb + i * 16 + fr);
#pragma unroll
    for (int i = 0; i < 4; ++i) bf[i] = LDB(bufR, bnb + i * 16 + fr);
    __builtin_amdgcn_s_setprio(1);
#pragma unroll
    for (int mi = 0; mi < 4; ++mi)
#pragma unroll
      for (int ni = 0; ni < 4; ++ni)
        acc[mi][ni] = __builtin_amdgcn_mfma_f32_16x16x32_bf16(
            af[mi], bf[ni], acc[mi][ni], 0, 0, 0);
    __builtin_amdgcn_s_setprio(0);
    asm volatile("s_waitcnt vmcnt(3)" ::: "memory");
    __builtin_amdgcn_sched_barrier(0);
    __builtin_amdgcn_s_barrier();
    bufR = (bufR == 2) ? 0 : bufR + 1;
    bufW = (bufW == 2) ? 0 : bufW + 1;
  }

  asm volatile("s_waitcnt vmcnt(0) lgkmcnt(0)" ::: "memory");
  __builtin_amdgcn_sched_barrier(0);
  __builtin_amdgcn_s_barrier();

  // ---------------- epilogue: D row=(l>>4)*4+j, col=l&15 --------------------
  const int r0 = (l >> 4) << 2;
  const int c0 = l & 15;
  const int mat = bn >> 2;                        // 0=q 1=k 2=v
  if (mat == 0) {
    u16* dst = dq;
    const size_t colbase = (size_t)(bn & 3) * 256 + (size_t)wn * 64;
#pragma unroll
    for (int mi = 0; mi < 4; ++mi) {
#pragma unroll
      for (int j = 0; j < 4; ++j) {
        float v0 = acc[mi][0][j], v1 = acc[mi][1][j];
        float v2 = acc[mi][2][j], v3 = acc[mi][3][j];
        float m = fmaxf(fmaxf(v0, v1), fmaxf(v2, v3));
#pragma unroll
        for (int off = 1; off < 16; off <<= 1) m = fmaxf(m, __shfl_xor(m, off));
        float e0 = __expf(v0 - m), e1 = __expf(v1 - m);
        float e2 = __expf(v2 - m), e3 = __expf(v3 - m);
        float s = e0 + e1 + e2 + e3;
#pragma unroll
        for (int off = 1; off < 16; off <<= 1) s += __shfl_xor(s, off);
        float inv = 1.f / s;
        const size_t row = arow0 + wm * 64 + mi * 16 + r0 + j;
        u16* p = dst + row * DIMN + colbase + c0;
        p[0]  = f2bf(e0 * inv); p[16] = f2bf(e1 * inv);
        p[32] = f2bf(e2 * inv); p[48] = f2bf(e3 * inv);
      }
    }
  } else {
    // k/v: stage C-tile in LDS as [col 256][t 132-pad], coalesced along t
    u16* dst = (mat == 1) ? dk : dv;
    u16* lt = (u16*)lds;
#pragma unroll
    for (int mi = 0; mi < 4; ++mi) {
      const int tl = wm * 64 + mi * 16 + r0;
#pragma unroll
      for (int ni = 0; ni < 4; ++ni) {
        const int cl = wn * 64 + ni * 16 + c0;
        s16x4 o;
#pragma unroll
        for (int j = 0; j < 4; ++j) {
          float v = acc[mi][ni][j];
          float r = (mat == 1) ? (v > 0.f ? v + 1.f : __expf(v)) : v;
          o[j] = (short)f2bf(r);
        }
        *(s16x4*)&lt[cl * 132 + tl] = o;
      }
    }
    __builtin_amdgcn_s_barrier();
    const int colb = (bn & 3) * 256;
    const int bb = (int)(arow0 >> 12);
    const int t0 = (int)(arow0 & 4095);
#pragma unroll
    for (int i = 0; i < 8; ++i) {
      const int chunk = i * 512 + tid;          // 4096 chunks
      const int cl = chunk >> 4;                // 0..255
      const int toct = (chunk & 15) * 8;
      s16x8 vv = *(const s16x8*)&lt[cl * 132 + toct];
      const int col = colb + cl;
      const int h = col >> 6, d = col & 63;
      *(s16x8*)&dst[((size_t)((bb * 16 + h) * 64 + d)) * 4096 + t0 + toct] = vv;
    }
  }
}

// ------------- OUT: 128x512 triple-buffered counted-vmcnt bf16 GEMM ---------
// dO[M][1024] = attn[M][1024] * woT[1024][1024]^T + bias.  BN=512 halves the
// A-panel re-fetch (N/BN = 2 vs 4) -> FETCH ~130 -> ~70MB.  8 waves 2Mx4N,
// per-wave 64x128 (acc[4][8]); BK=32; LDS 3 x 40KB dynamic; vmcnt(5) depth-2.
__global__ __launch_bounds__(512, 2) void gemm_o(
    const u16* __restrict__ A, const u16* __restrict__ Bt,
    float* __restrict__ dO, const float* __restrict__ bias) {
  constexpr int K = 1024;
  constexpr int NT = K / 32;                  // 32 K-steps
  extern __shared__ char lds[];               // 3 x 40960

  const int tid = threadIdx.x;
  const int l = tid & 63;
  const int w = tid >> 6;
  const int wm = w >> 2;           // 0..1 (64 rows each)
  const int wn = w & 3;            // 0..3 (128 cols each)

  const int xcd = (int)blockIdx.x & 7;
  const int idx = (int)blockIdx.x >> 3;       // 0..31
  const int bm = xcd * 16 + (idx & 15);       // 0..127
  const int bn = idx >> 4;                    // 0..1
  const size_t arow0 = (size_t)bm * 128;
  const size_t brow0 = (size_t)bn * 512;

  int lrowA, lcolA, lrowB[4], lcolB[4];
  {
    int lg2 = swz16k(tid * 16);
    lrowA = lg2 >> 6; lcolA = (lg2 & 63) >> 1;
#pragma unroll
    for (int i = 0; i < 4; ++i) {
      int lb = swz16k((i * 512 + tid) * 16);
      lrowB[i] = lb >> 6; lcolB[i] = (lb & 63) >> 1;
    }
  }

  const int fr = l & 15;
  const int kswz = (((l >> 4) << 4)) ^ ((((fr >> 1) & 3)) << 4);

  auto STAGE = [&](int buf, int tt) {
    const int kbase = (tt & (NT - 1)) * 32;
    {
      const u16* src = A + (arow0 + (size_t)lrowA) * K + kbase + lcolA;
      char* dst = lds + (buf * 40960 + tid * 16);
      __builtin_amdgcn_global_load_lds(
          (__attribute__((address_space(1))) const void*)src,
          (__attribute__((address_space(3))) void*)dst, 16, 0, 0);
    }
#pragma unroll
    for (int i = 0; i < 4; ++i) {
      const u16* src = Bt + (brow0 + (size_t)lrowB[i]) * K + kbase + lcolB[i];
      char* dst = lds + (buf * 40960 + 8192 + (i * 512 + tid) * 16);
      __builtin_amdgcn_global_load_lds(
          (__attribute__((address_space(1))) const void*)src,
          (__attribute__((address_space(3))) void*)dst, 16, 0, 0);
    }
  };
  auto LDA = [&](int buf, int rowb) -> s16x8 {
    return *(const s16x8*)(lds + buf * 40960 + rowb * 64 + kswz);
  };
  auto LDB = [&](int buf, int rowb) -> s16x8 {
    return *(const s16x8*)(lds + buf * 40960 + 8192 + rowb * 64 + kswz);
  };

  f32x4 acc[4][8];
#pragma unroll
  for (int i = 0; i < 4; ++i)
#pragma unroll
    for (int j = 0; j < 8; ++j) acc[i][j] = {0.f, 0.f, 0.f, 0.f};

  STAGE(0, 0);
  STAGE(1, 1);
  asm volatile("s_waitcnt vmcnt(5)" ::: "memory");
  __builtin_amdgcn_sched_barrier(0);
  __builtin_amdgcn_s_barrier();

  const int amb = wm * 64;
  const int bnb = wn * 128;
  s16x8 af[4], bf[8];

  int bufR = 0, bufW = 2;
#pragma unroll 1
  for (int t = 0; t < NT; ++t) {
    STAGE(bufW, t + 2);
#pragma unroll
    for (int i = 0; i < 4; ++i) af[i] = LDA(bufR, amb + i * 16 + fr);
#pragma unroll
    for (int i = 0; i < 8; ++i) bf[i] = LDB(bufR, bnb + i * 16 + fr);
    __builtin_amdgcn_s_setprio(1);
#pragma unroll
    for (int mi = 0; mi < 4; ++mi)
#pragma unroll
      for (int ni = 0; ni < 8; ++ni)
        acc[mi][ni] = __builtin_amdgcn_mfma_f32_16x16x32_bf16(
            af[mi], bf[ni], acc[mi][ni], 0, 0, 0);
    __builtin_amdgcn_s_setprio(0);
    asm volatile("s_waitcnt vmcnt(5)" ::: "memory");
    __builtin_amdgcn_sched_barrier(0);
    __builtin_amdgcn_s_barrier();
    bufR = (bufR == 2) ? 0 : bufR + 1;
    bufW = (bufW == 2) ? 0 : bufW + 1;
  }

  // epilogue: direct f32 stores (+bias)
  const int r0 = (l >> 4) << 2;
  const int c0 = l & 15;
#pragma unroll
  for (int mi = 0; mi < 4; ++mi)
#pragma unroll
    for (int ni = 0; ni < 8; ++ni) {
      const size_t col = brow0 + (size_t)wn * 128 + ni * 16 + c0;
      const float bv = bias[col];
#pragma unroll
      for (int j = 0; j < 4; ++j) {
        const size_t row = arow0 + wm * 64 + mi * 16 + r0 + j;
        dO[row * DIMN + col] = acc[mi][ni][j] + bv;
      }
    }
}

// -------------------- fused middle v2: producer/consumer waves --------------
// (unchanged from R12 — verified)
__global__ __launch_bounds__(512) void mid_fused_kern(const u16* __restrict__ kT,
                                                      const u16* __restrict__ vT,
                                                      const u16* __restrict__ qb,
                                                      u16* __restrict__ attn) {
  __shared__ u16 cprev[2][16][72];   // bf16 [e][d], 144B rows (16B-aligned)
  const int tid = threadIdx.x;
  const int l = tid & 63;
  const int w = tid >> 6;           // 0..7
  const int ws = w & 3;
  const bool isCtx = w < 4;
  const int fr = l & 15;
  const int lg = l >> 4;            // 0..3

  const int bid = (int)blockIdx.x;
  const int xcd = bid & 7;
  const int slot = bid >> 3;        // 0..31
  const int bh = xcd * 8 + (slot >> 2);
  const int eg = slot & 3;
  const int b = bh >> 4, h = bh & 15;

  const size_t kvbase = (size_t)bh * 64 * 4096;   // [d][t]
  const size_t qrow0 = (size_t)b * T_LEN;

  if (isCtx) {
#pragma unroll
    for (int j = 0; j < 4; ++j) cprev[0][lg * 4 + j][ws * 16 + fr] = 0;
  }
  __syncthreads();

  if (isCtx) {
    auto LV = [&](int u, int kk) -> s16x8 {   // vT rows e (A operand)
      return *(const s16x8*)&vT[kvbase + (size_t)(eg * 16 + fr) * 4096 +
                                u * 64 + kk * 32 + lg * 8];
    };
    auto LK = [&](int u, int kk) -> s16x8 {   // kT rows d (B operand)
      return *(const s16x8*)&kT[kvbase + (size_t)(ws * 16 + fr) * 4096 +
                                u * 64 + kk * 32 + lg * 8];
    };
    f32x4 cacc = {0.f, 0.f, 0.f, 0.f};   // rows e=lg*4+j, col d=ws*16+fr
    float ksum = 0.f;
    s16x8 vA0 = LV(0, 0), vA1 = LV(0, 1);
    s16x8 kB0 = LK(0, 0), kB1 = LK(0, 1);
#pragma unroll 1
    for (int u = 0; u < 64; ++u) {
      const s16x8 cvA0 = vA0, cvA1 = vA1, ckB0 = kB0, ckB1 = kB1;
      if (u < 63) {
        vA0 = LV(u + 1, 0); vA1 = LV(u + 1, 1);
        kB0 = LK(u + 1, 0); kB1 = LK(u + 1, 1);
      }
      cacc = __builtin_amdgcn_mfma_f32_16x16x32_bf16(cvA0, ckB0, cacc, 0, 0, 0);
      cacc = __builtin_amdgcn_mfma_f32_16x16x32_bf16(cvA1, ckB1, cacc, 0, 0, 0);
      float s = 0.f;
#pragma unroll
      for (int j = 0; j < 8; ++j)
        s += bf2f((u16)ckB0[j]) + bf2f((u16)ckB1[j]);
      s += __shfl_xor(s, 16);
      s += __shfl_xor(s, 32);
      ksum += s;
      const float inv = 1.f / (ksum + 1e-6f);
      u16* pp = &cprev[(u + 1) & 1][lg * 4][ws * 16 + fr];
#pragma unroll
      for (int j = 0; j < 4; ++j) pp[j * 72] = f2bf(cacc[j] * inv);
      __syncthreads();
    }
  } else {
    auto LQ = [&](int u, int kk) -> s16x8 {   // q rows n (A operand)
      return *(const s16x8*)&qb[(qrow0 + u * 64 + ws * 16 + fr) * DIMN +
                                (size_t)h * 64 + kk * 32 + lg * 8];
    };
    s16x8 qA0 = LQ(0, 0), qA1 = LQ(0, 1);
#pragma unroll 1
    for (int u = 0; u < 64; ++u) {
      const s16x8 cqA0 = qA0, cqA1 = qA1;
      if (u < 63) { qA0 = LQ(u + 1, 0); qA1 = LQ(u + 1, 1); }
      s16x8 cB0 = *(const s16x8*)&cprev[u & 1][fr][lg * 8];
      s16x8 cB1 = *(const s16x8*)&cprev[u & 1][fr][32 + lg * 8];
      f32x4 aacc = {0.f, 0.f, 0.f, 0.f};
      aacc = __builtin_amdgcn_mfma_f32_16x16x32_bf16(cqA0, cB0, aacc, 0, 0, 0);
      aacc = __builtin_amdgcn_mfma_f32_16x16x32_bf16(cqA1, cB1, aacc, 0, 0, 0);
      const size_t arow = qrow0 + (size_t)u * 64 + ws * 16 + lg * 4;
#pragma unroll
      for (int j = 0; j < 4; ++j)
        attn[(arow + j) * DIMN + (size_t)h * 64 + eg * 16 + fr] = f2bf(aacc[j]);
      __syncthreads();
    }
  }
}

// ---------------------------------------------------------------------------
extern "C" void kernel_launch(void* const* d_in, const int* in_sizes, int n_in,
                              void* d_out, int out_size, void* d_ws, size_t ws_size,
                              hipStream_t stream) {
  const float* x  = (const float*)d_in[0];
  const float* Wq = (const float*)d_in[1];
  const float* Wk = (const float*)d_in[2];
  const float* Wv = (const float*)d_in[3];
  const float* Wo = (const float*)d_in[4];
  const float* bo = (const float*)d_in[5];
  float* out = (float*)d_out;

  constexpr size_t SZ_XB = (size_t)MROWS * DIMN * 2;
  constexpr size_t SZ_WT = (size_t)DIMN * DIMN * 2;
  char* ws = (char*)d_ws;
  u16*   xb   = (u16*)(ws);
  u16*   wqT  = (u16*)(ws + SZ_XB);          // wq/wk/wv/wo contiguous
  u16*   woT  = (u16*)(ws + SZ_XB + 3 * SZ_WT);
  u16*   qb   = (u16*)(ws + SZ_XB + 4 * SZ_WT);
  u16*   kT   = (u16*)(ws + 2 * SZ_XB + 4 * SZ_WT);   // [bh][d][t]
  u16*   vT   = (u16*)(ws + 3 * SZ_XB + 4 * SZ_WT);   // [bh][d][t]
  u16*   attn = xb;  // xb dead after QKV GEMM

  (void)hipFuncSetAttribute((const void*)gemm_o,
                            hipFuncAttributeMaxDynamicSharedMemorySize, 122880);

  cvt_all_kern<<<1024 + MROWS * DIMN / 1024, 256, 0, stream>>>(x, Wq, Wk, Wv, Wo,
                                                               wqT, xb);

  // fused QKV: N = 3072, grid 128 x 12 = 1536
  gemm_qkv<<<1536, 512, 0, stream>>>(xb, wqT, qb, kT, vT);

  // fused middle: ctx + cumnorm + attn, one pass, producer/consumer waves
  mid_fused_kern<<<256, 512, 0, stream>>>(kT, vT, qb, attn);

  // output: N = 1024, grid 128 x 2 = 256, BN=512
  gemm_o<<<256, 512, 122880, stream>>>(attn, woT, out, bo);
}

// Round 15
// 237.009 us; speedup vs baseline: 1.1887x; 1.0347x over previous
//
#include <hip/hip_runtime.h>

// ---------------------------------------------------------------------------
// LinearSelfAttention: B=4 T=4096 DIM=1024 H=16 E=64 BUCKET=64 U=64
// ---------------------------------------------------------------------------

#define T_LEN 4096
#define DIMN  1024
#define NHEAD 16
#define NB    4
#define MROWS (NB * T_LEN)   // 16384

typedef float f32x4 __attribute__((ext_vector_type(4)));
typedef short s16x8 __attribute__((ext_vector_type(8)));
typedef short s16x4 __attribute__((ext_vector_type(4)));
using u16 = unsigned short;

__device__ __forceinline__ u16 f2bf(float f) {
  unsigned int u = __float_as_uint(f);
  u += 0x7fffu + ((u >> 16) & 1u);   // RNE
  return (u16)(u >> 16);
}
__device__ __forceinline__ float bf2f(u16 h) {
  return __uint_as_float(((unsigned int)h) << 16);
}
// involution swizzle within a slot ([rows][32 bf16] = row*64B); row-pair-local.
__device__ __forceinline__ int swz16k(int off) {
  return off ^ (((off >> 7) & 3) << 4);
}

// ------------------- fused weight transpose+cast AND x cast ----------------
__global__ __launch_bounds__(256) void cvt_all_kern(const float* __restrict__ x,
                                                    const float* __restrict__ W0,
                                                    const float* __restrict__ W1,
                                                    const float* __restrict__ W2,
                                                    const float* __restrict__ W3,
                                                    u16* __restrict__ WT,
                                                    u16* __restrict__ xb) {
  __shared__ float tile[64][65];
  const int tid = threadIdx.x;
  if (blockIdx.x < 1024) {
    const int blk = blockIdx.x & 255;
    const int sel = blockIdx.x >> 8;
    const float* W = (sel == 0) ? W0 : (sel == 1) ? W1 : (sel == 2) ? W2 : W3;
    u16* dst = WT + (size_t)sel * DIMN * DIMN;
    const int k0 = (blk >> 4) << 6;
    const int n0 = (blk & 15) << 6;
    const int r = tid >> 6;
    const int c = tid & 63;
#pragma unroll
    for (int i = 0; i < 16; ++i) {
      int row = (i << 2) + r;
      tile[row][c] = W[(size_t)(k0 + row) * DIMN + n0 + c];
    }
    __syncthreads();
#pragma unroll
    for (int i = 0; i < 16; ++i) {
      int row = (i << 2) + r;
      dst[(size_t)(n0 + row) * DIMN + k0 + c] = f2bf(tile[c][row]);
    }
  } else {
    size_t i = ((size_t)(blockIdx.x - 1024) * 256 + tid) * 4;
    f32x4 v = *(const f32x4*)(x + i);
    s16x4 o;
    o.x = (short)f2bf(v.x); o.y = (short)f2bf(v.y);
    o.z = (short)f2bf(v.z); o.w = (short)f2bf(v.w);
    *(s16x4*)(xb + i) = o;
  }
}

// ------------- QKV: 128x256 triple-buffered counted-vmcnt bf16 GEMM ---------
// (R14 verified — frozen)
__global__ __launch_bounds__(512, 4) void gemm_qkv(
    const u16* __restrict__ A, const u16* __restrict__ Bt,
    u16* __restrict__ dq, u16* __restrict__ dk, u16* __restrict__ dv) {
  constexpr int K = 1024;
  constexpr int BNT = 12;                     // N / 256
  constexpr int NT = K / 32;                  // 32 K-steps
  __shared__ char lds[73728];                 // 3 x 24576; reused by epilogue

  const int tid = threadIdx.x;
  const int l = tid & 63;
  const int w = tid >> 6;
  const int wm = w >> 2;
  const int wn = w & 3;

  const int xcd = (int)blockIdx.x & 7;
  const int idx = (int)blockIdx.x >> 3;
  const int g = idx / (4 * BNT);
  const int r2 = idx % (4 * BNT);
  const int bn = r2 >> 2;
  const int bm = xcd * 16 + g * 4 + (r2 & 3);
  const size_t arow0 = (size_t)bm * 128;
  const size_t brow0 = (size_t)bn * 256;

  int lrow[2], lcol[2];
#pragma unroll
  for (int i = 0; i < 2; ++i) {
    int lg2 = swz16k((i * 512 + tid) * 16);
    lrow[i] = lg2 >> 6;
    lcol[i] = (lg2 & 63) >> 1;
  }

  const int fr = l & 15;
  const int kswz = (((l >> 4) << 4)) ^ ((((fr >> 1) & 3)) << 4);

  auto STAGE = [&](int buf, int matsel, int tt) {
    const int kbase = (tt & (NT - 1)) * 32;
#pragma unroll
    for (int i = 0; i < 2; ++i) {
      if (matsel == 0 && i == 1) break;
      const u16* src = (matsel == 0)
          ? A  + (arow0 + (size_t)lrow[i]) * K + kbase + lcol[i]
          : Bt + (brow0 + (size_t)lrow[i]) * K + kbase + lcol[i];
      char* dst = lds + (buf * 24576 + matsel * 8192 + (i * 512 + tid) * 16);
      __builtin_amdgcn_global_load_lds(
          (__attribute__((address_space(1))) const void*)src,
          (__attribute__((address_space(3))) void*)dst, 16, 0, 0);
    }
  };
  auto LDA = [&](int buf, int rowb) -> s16x8 {
    return *(const s16x8*)(lds + buf * 24576 + rowb * 64 + kswz);
  };
  auto LDB = [&](int buf, int rowb) -> s16x8 {
    return *(const s16x8*)(lds + buf * 24576 + 8192 + rowb * 64 + kswz);
  };

  f32x4 acc[4][4];
#pragma unroll
  for (int i = 0; i < 4; ++i)
#pragma unroll
    for (int j = 0; j < 4; ++j) acc[i][j] = {0.f, 0.f, 0.f, 0.f};

  STAGE(0, 0, 0); STAGE(0, 1, 0);
  STAGE(1, 0, 1); STAGE(1, 1, 1);
  asm volatile("s_waitcnt vmcnt(3)" ::: "memory");
  __builtin_amdgcn_sched_barrier(0);
  __builtin_amdgcn_s_barrier();

  const int amb = wm * 64;
  const int bnb = wn * 64;
  s16x8 af[4], bf[4];

  int bufR = 0, bufW = 2;
#pragma unroll 1
  for (int t = 0; t < NT; ++t) {
    STAGE(bufW, 0, t + 2);
    STAGE(bufW, 1, t + 2);
#pragma unroll
    for (int i = 0; i < 4; ++i) af[i] = LDA(bufR, amb + i * 16 + fr);
#pragma unroll
    for (int i = 0; i < 4; ++i) bf[i] = LDB(bufR, bnb + i * 16 + fr);
    __builtin_amdgcn_s_setprio(1);
#pragma unroll
    for (int mi = 0; mi < 4; ++mi)
#pragma unroll
      for (int ni = 0; ni < 4; ++ni)
        acc[mi][ni] = __builtin_amdgcn_mfma_f32_16x16x32_bf16(
            af[mi], bf[ni], acc[mi][ni], 0, 0, 0);
    __builtin_amdgcn_s_setprio(0);
    asm volatile("s_waitcnt vmcnt(3)" ::: "memory");
    __builtin_amdgcn_sched_barrier(0);
    __builtin_amdgcn_s_barrier();
    bufR = (bufR == 2) ? 0 : bufR + 1;
    bufW = (bufW == 2) ? 0 : bufW + 1;
  }

  asm volatile("s_waitcnt vmcnt(0) lgkmcnt(0)" ::: "memory");
  __builtin_amdgcn_sched_barrier(0);
  __builtin_amdgcn_s_barrier();

  const int r0 = (l >> 4) << 2;
  const int c0 = l & 15;
  const int mat = bn >> 2;                        // 0=q 1=k 2=v
  if (mat == 0) {
    u16* dst = dq;
    const size_t colbase = (size_t)(bn & 3) * 256 + (size_t)wn * 64;
#pragma unroll
    for (int mi = 0; mi < 4; ++mi) {
#pragma unroll
      for (int j = 0; j < 4; ++j) {
        float v0 = acc[mi][0][j], v1 = acc[mi][1][j];
        float v2 = acc[mi][2][j], v3 = acc[mi][3][j];
        float m = fmaxf(fmaxf(v0, v1), fmaxf(v2, v3));
#pragma unroll
        for (int off = 1; off < 16; off <<= 1) m = fmaxf(m, __shfl_xor(m, off));
        float e0 = __expf(v0 - m), e1 = __expf(v1 - m);
        float e2 = __expf(v2 - m), e3 = __expf(v3 - m);
        float s = e0 + e1 + e2 + e3;
#pragma unroll
        for (int off = 1; off < 16; off <<= 1) s += __shfl_xor(s, off);
        float inv = 1.f / s;
        const size_t row = arow0 + wm * 64 + mi * 16 + r0 + j;
        u16* p = dst + row * DIMN + colbase + c0;
        p[0]  = f2bf(e0 * inv); p[16] = f2bf(e1 * inv);
        p[32] = f2bf(e2 * inv); p[48] = f2bf(e3 * inv);
      }
    }
  } else {
    u16* dst = (mat == 1) ? dk : dv;
    u16* lt = (u16*)lds;
#pragma unroll
    for (int mi = 0; mi < 4; ++mi) {
      const int tl = wm * 64 + mi * 16 + r0;
#pragma unroll
      for (int ni = 0; ni < 4; ++ni) {
        const int cl = wn * 64 + ni * 16 + c0;
        s16x4 o;
#pragma unroll
        for (int j = 0; j < 4; ++j) {
          float v = acc[mi][ni][j];
          float r = (mat == 1) ? (v > 0.f ? v + 1.f : __expf(v)) : v;
          o[j] = (short)f2bf(r);
        }
        *(s16x4*)&lt[cl * 132 + tl] = o;
      }
    }
    __builtin_amdgcn_s_barrier();
    const int colb = (bn & 3) * 256;
    const int bb = (int)(arow0 >> 12);
    const int t0 = (int)(arow0 & 4095);
#pragma unroll
    for (int i = 0; i < 8; ++i) {
      const int chunk = i * 512 + tid;          // 4096 chunks
      const int cl = chunk >> 4;                // 0..255
      const int toct = (chunk & 15) * 8;
      s16x8 vv = *(const s16x8*)&lt[cl * 132 + toct];
      const int col = colb + cl;
      const int h = col >> 6, d = col & 63;
      *(s16x8*)&dst[((size_t)((bb * 16 + h) * 64 + d)) * 4096 + t0 + toct] = vv;
    }
  }
}

// ------------- OUT: 128x512 triple-buffered counted-vmcnt bf16 GEMM ---------
// (R14 — frozen)
__global__ __launch_bounds__(512, 2) void gemm_o(
    const u16* __restrict__ A, const u16* __restrict__ Bt,
    float* __restrict__ dO, const float* __restrict__ bias) {
  constexpr int K = 1024;
  constexpr int NT = K / 32;                  // 32 K-steps
  extern __shared__ char lds[];               // 3 x 40960

  const int tid = threadIdx.x;
  const int l = tid & 63;
  const int w = tid >> 6;
  const int wm = w >> 2;
  const int wn = w & 3;

  const int xcd = (int)blockIdx.x & 7;
  const int idx = (int)blockIdx.x >> 3;       // 0..31
  const int bm = xcd * 16 + (idx & 15);       // 0..127
  const int bn = idx >> 4;                    // 0..1
  const size_t arow0 = (size_t)bm * 128;
  const size_t brow0 = (size_t)bn * 512;

  int lrowA, lcolA, lrowB[4], lcolB[4];
  {
    int lg2 = swz16k(tid * 16);
    lrowA = lg2 >> 6; lcolA = (lg2 & 63) >> 1;
#pragma unroll
    for (int i = 0; i < 4; ++i) {
      int lb = swz16k((i * 512 + tid) * 16);
      lrowB[i] = lb >> 6; lcolB[i] = (lb & 63) >> 1;
    }
  }

  const int fr = l & 15;
  const int kswz = (((l >> 4) << 4)) ^ ((((fr >> 1) & 3)) << 4);

  auto STAGE = [&](int buf, int tt) {
    const int kbase = (tt & (NT - 1)) * 32;
    {
      const u16* src = A + (arow0 + (size_t)lrowA) * K + kbase + lcolA;
      char* dst = lds + (buf * 40960 + tid * 16);
      __builtin_amdgcn_global_load_lds(
          (__attribute__((address_space(1))) const void*)src,
          (__attribute__((address_space(3))) void*)dst, 16, 0, 0);
    }
#pragma unroll
    for (int i = 0; i < 4; ++i) {
      const u16* src = Bt + (brow0 + (size_t)lrowB[i]) * K + kbase + lcolB[i];
      char* dst = lds + (buf * 40960 + 8192 + (i * 512 + tid) * 16);
      __builtin_amdgcn_global_load_lds(
          (__attribute__((address_space(1))) const void*)src,
          (__attribute__((address_space(3))) void*)dst, 16, 0, 0);
    }
  };
  auto LDA = [&](int buf, int rowb) -> s16x8 {
    return *(const s16x8*)(lds + buf * 40960 + rowb * 64 + kswz);
  };
  auto LDB = [&](int buf, int rowb) -> s16x8 {
    return *(const s16x8*)(lds + buf * 40960 + 8192 + rowb * 64 + kswz);
  };

  f32x4 acc[4][8];
#pragma unroll
  for (int i = 0; i < 4; ++i)
#pragma unroll
    for (int j = 0; j < 8; ++j) acc[i][j] = {0.f, 0.f, 0.f, 0.f};

  STAGE(0, 0);
  STAGE(1, 1);
  asm volatile("s_waitcnt vmcnt(5)" ::: "memory");
  __builtin_amdgcn_sched_barrier(0);
  __builtin_amdgcn_s_barrier();

  const int amb = wm * 64;
  const int bnb = wn * 128;
  s16x8 af[4], bf[8];

  int bufR = 0, bufW = 2;
#pragma unroll 1
  for (int t = 0; t < NT; ++t) {
    STAGE(bufW, t + 2);
#pragma unroll
    for (int i = 0; i < 4; ++i) af[i] = LDA(bufR, amb + i * 16 + fr);
#pragma unroll
    for (int i = 0; i < 8; ++i) bf[i] = LDB(bufR, bnb + i * 16 + fr);
    __builtin_amdgcn_s_setprio(1);
#pragma unroll
    for (int mi = 0; mi < 4; ++mi)
#pragma unroll
      for (int ni = 0; ni < 8; ++ni)
        acc[mi][ni] = __builtin_amdgcn_mfma_f32_16x16x32_bf16(
            af[mi], bf[ni], acc[mi][ni], 0, 0, 0);
    __builtin_amdgcn_s_setprio(0);
    asm volatile("s_waitcnt vmcnt(5)" ::: "memory");
    __builtin_amdgcn_sched_barrier(0);
    __builtin_amdgcn_s_barrier();
    bufR = (bufR == 2) ? 0 : bufR + 1;
    bufW = (bufW == 2) ? 0 : bufW + 1;
  }

  const int r0 = (l >> 4) << 2;
  const int c0 = l & 15;
#pragma unroll
  for (int mi = 0; mi < 4; ++mi)
#pragma unroll
    for (int ni = 0; ni < 8; ++ni) {
      const size_t col = brow0 + (size_t)wn * 128 + ni * 16 + c0;
      const float bv = bias[col];
#pragma unroll
      for (int j = 0; j < 4; ++j) {
        const size_t row = arow0 + wm * 64 + mi * 16 + r0 + j;
        dO[row * DIMN + col] = acc[mi][ni][j] + bv;
      }
    }
}

// ------------- fused middle v3: 2 buckets/iter, 4-buffer ping-pong ----------
// Block = (bh, eg), 512 thr = 8 waves (4 ctx + 4 attn).  Iteration t handles
// buckets 2t,2t+1: ctx publishes C_prev(2t) and C_prev(2t+1) into bufs
// (2t)&3,(2t+1)&3, accumulating cacc/ksum in registers; attn runs one
// iteration behind, reading bufs (2t-2)&3,(2t-1)&3 (disjoint mod 4).
// ONE barrier per 2 buckets (64 -> 33).  Loop t=0..32; ctx active t<32,
// attn active t>=1 (wave-uniform guards; barrier outside guards).
__global__ __launch_bounds__(512) void mid_fused_kern(const u16* __restrict__ kT,
                                                      const u16* __restrict__ vT,
                                                      const u16* __restrict__ qb,
                                                      u16* __restrict__ attn) {
  __shared__ u16 cprev[4][16][72];   // bf16 [e][d], 144B rows
  const int tid = threadIdx.x;
  const int l = tid & 63;
  const int w = tid >> 6;           // 0..7
  const int ws = w & 3;
  const bool isCtx = w < 4;
  const int fr = l & 15;
  const int lg = l >> 4;            // 0..3

  const int bid = (int)blockIdx.x;
  const int xcd = bid & 7;
  const int slot = bid >> 3;        // 0..31
  const int bh = xcd * 8 + (slot >> 2);
  const int eg = slot & 3;
  const int b = bh >> 4, h = bh & 15;

  const size_t kvbase = (size_t)bh * 64 * 4096;   // [d][t]
  const size_t qrow0 = (size_t)b * T_LEN;

  if (isCtx) {
    auto LV = [&](int u, int kk) -> s16x8 {   // vT rows e (A operand)
      return *(const s16x8*)&vT[kvbase + (size_t)(eg * 16 + fr) * 4096 +
                                u * 64 + kk * 32 + lg * 8];
    };
    auto LK = [&](int u, int kk) -> s16x8 {   // kT rows d (B operand)
      return *(const s16x8*)&kT[kvbase + (size_t)(ws * 16 + fr) * 4096 +
                                u * 64 + kk * 32 + lg * 8];
    };
    f32x4 cacc = {0.f, 0.f, 0.f, 0.f};   // rows e=lg*4+j, col d=ws*16+fr
    float ksum = 0.f;
    s16x8 vA00 = LV(0, 0), vA01 = LV(0, 1), vA10 = LV(1, 0), vA11 = LV(1, 1);
    s16x8 kB00 = LK(0, 0), kB01 = LK(0, 1), kB10 = LK(1, 0), kB11 = LK(1, 1);
#pragma unroll 1
    for (int t = 0; t <= 32; ++t) {
      if (t < 32) {
        const s16x8 a00 = vA00, a01 = vA01, a10 = vA10, a11 = vA11;
        const s16x8 b00 = kB00, b01 = kB01, b10 = kB10, b11 = kB11;
        if (t < 31) {
          vA00 = LV(2 * t + 2, 0); vA01 = LV(2 * t + 2, 1);
          vA10 = LV(2 * t + 3, 0); vA11 = LV(2 * t + 3, 1);
          kB00 = LK(2 * t + 2, 0); kB01 = LK(2 * t + 2, 1);
          kB10 = LK(2 * t + 3, 0); kB11 = LK(2 * t + 3, 1);
        }
        // bucket 2t: publish C through 2t-1, then accumulate S_2t
        {
          const float inv = 1.f / (ksum + 1e-6f);
          u16* pp = &cprev[(2 * t) & 3][lg * 4][ws * 16 + fr];
#pragma unroll
          for (int j = 0; j < 4; ++j) pp[j * 72] = f2bf(cacc[j] * inv);
          cacc = __builtin_amdgcn_mfma_f32_16x16x32_bf16(a00, b00, cacc, 0, 0, 0);
          cacc = __builtin_amdgcn_mfma_f32_16x16x32_bf16(a01, b01, cacc, 0, 0, 0);
          float s = 0.f;
#pragma unroll
          for (int j = 0; j < 8; ++j)
            s += bf2f((u16)b00[j]) + bf2f((u16)b01[j]);
          s += __shfl_xor(s, 16);
          s += __shfl_xor(s, 32);
          ksum += s;
        }
        // bucket 2t+1: publish C through 2t, then accumulate S_{2t+1}
        {
          const float inv = 1.f / (ksum + 1e-6f);
          u16* pp = &cprev[(2 * t + 1) & 3][lg * 4][ws * 16 + fr];
#pragma unroll
          for (int j = 0; j < 4; ++j) pp[j * 72] = f2bf(cacc[j] * inv);
          cacc = __builtin_amdgcn_mfma_f32_16x16x32_bf16(a10, b10, cacc, 0, 0, 0);
          cacc = __builtin_amdgcn_mfma_f32_16x16x32_bf16(a11, b11, cacc, 0, 0, 0);
          float s = 0.f;
#pragma unroll
          for (int j = 0; j < 8; ++j)
            s += bf2f((u16)b10[j]) + bf2f((u16)b11[j]);
          s += __shfl_xor(s, 16);
          s += __shfl_xor(s, 32);
          ksum += s;
        }
      }
      __syncthreads();
    }
  } else {
    auto LQ = [&](int u, int kk) -> s16x8 {   // q rows n (A operand)
      return *(const s16x8*)&qb[(qrow0 + u * 64 + ws * 16 + fr) * DIMN +
                                (size_t)h * 64 + kk * 32 + lg * 8];
    };
    s16x8 q00 = LQ(0, 0), q01 = LQ(0, 1), q10 = LQ(1, 0), q11 = LQ(1, 1);
#pragma unroll 1
    for (int t = 0; t <= 32; ++t) {
      if (t >= 1) {
        const s16x8 c00 = q00, c01 = q01, c10 = q10, c11 = q11;
        if (t < 32) {
          q00 = LQ(2 * t, 0); q01 = LQ(2 * t, 1);
          q10 = LQ(2 * t + 1, 0); q11 = LQ(2 * t + 1, 1);
        }
        // bucket 2(t-1)
        {
          const int u = 2 * (t - 1);
          s16x8 cB0 = *(const s16x8*)&cprev[u & 3][fr][lg * 8];
          s16x8 cB1 = *(const s16x8*)&cprev[u & 3][fr][32 + lg * 8];
          f32x4 aacc = {0.f, 0.f, 0.f, 0.f};
          aacc = __builtin_amdgcn_mfma_f32_16x16x32_bf16(c00, cB0, aacc, 0, 0, 0);
          aacc = __builtin_amdgcn_mfma_f32_16x16x32_bf16(c01, cB1, aacc, 0, 0, 0);
          const size_t arow = qrow0 + (size_t)u * 64 + ws * 16 + lg * 4;
#pragma unroll
          for (int j = 0; j < 4; ++j)
            attn[(arow + j) * DIMN + (size_t)h * 64 + eg * 16 + fr] =
                f2bf(aacc[j]);
        }
        // bucket 2(t-1)+1
        {
          const int u = 2 * (t - 1) + 1;
          s16x8 cB0 = *(const s16x8*)&cprev[u & 3][fr][lg * 8];
          s16x8 cB1 = *(const s16x8*)&cprev[u & 3][fr][32 + lg * 8];
          f32x4 aacc = {0.f, 0.f, 0.f, 0.f};
          aacc = __builtin_amdgcn_mfma_f32_16x16x32_bf16(c10, cB0, aacc, 0, 0, 0);
          aacc = __builtin_amdgcn_mfma_f32_16x16x32_bf16(c11, cB1, aacc, 0, 0, 0);
          const size_t arow = qrow0 + (size_t)u * 64 + ws * 16 + lg * 4;
#pragma unroll
          for (int j = 0; j < 4; ++j)
            attn[(arow + j) * DIMN + (size_t)h * 64 + eg * 16 + fr] =
                f2bf(aacc[j]);
        }
      }
      __syncthreads();
    }
  }
}

// ---------------------------------------------------------------------------
extern "C" void kernel_launch(void* const* d_in, const int* in_sizes, int n_in,
                              void* d_out, int out_size, void* d_ws, size_t ws_size,
                              hipStream_t stream) {
  const float* x  = (const float*)d_in[0];
  const float* Wq = (const float*)d_in[1];
  const float* Wk = (const float*)d_in[2];
  const float* Wv = (const float*)d_in[3];
  const float* Wo = (const float*)d_in[4];
  const float* bo = (const float*)d_in[5];
  float* out = (float*)d_out;

  constexpr size_t SZ_XB = (size_t)MROWS * DIMN * 2;
  constexpr size_t SZ_WT = (size_t)DIMN * DIMN * 2;
  char* ws = (char*)d_ws;
  u16*   xb   = (u16*)(ws);
  u16*   wqT  = (u16*)(ws + SZ_XB);          // wq/wk/wv/wo contiguous
  u16*   woT  = (u16*)(ws + SZ_XB + 3 * SZ_WT);
  u16*   qb   = (u16*)(ws + SZ_XB + 4 * SZ_WT);
  u16*   kT   = (u16*)(ws + 2 * SZ_XB + 4 * SZ_WT);   // [bh][d][t]
  u16*   vT   = (u16*)(ws + 3 * SZ_XB + 4 * SZ_WT);   // [bh][d][t]
  u16*   attn = xb;  // xb dead after QKV GEMM

  (void)hipFuncSetAttribute((const void*)gemm_o,
                            hipFuncAttributeMaxDynamicSharedMemorySize, 122880);

  cvt_all_kern<<<1024 + MROWS * DIMN / 1024, 256, 0, stream>>>(x, Wq, Wk, Wv, Wo,
                                                               wqT, xb);

  // fused QKV: N = 3072, grid 128 x 12 = 1536
  gemm_qkv<<<1536, 512, 0, stream>>>(xb, wqT, qb, kT, vT);

  // fused middle: ctx + cumnorm + attn, 2 buckets/iter, 4-buffer ping-pong
  mid_fused_kern<<<256, 512, 0, stream>>>(kT, vT, qb, attn);

  // output: N = 1024, grid 128 x 2 = 256, BN=512
  gemm_o<<<256, 512, 122880, stream>>>(attn, woT, out, bo);
}

// Round 16
// 235.362 us; speedup vs baseline: 1.1970x; 1.0070x over previous
//
#include <hip/hip_runtime.h>

// ---------------------------------------------------------------------------
// LinearSelfAttention: B=4 T=4096 DIM=1024 H=16 E=64 BUCKET=64 U=64
// ---------------------------------------------------------------------------

#define T_LEN 4096
#define DIMN  1024
#define NHEAD 16
#define NB    4
#define MROWS (NB * T_LEN)   // 16384

typedef float f32x4 __attribute__((ext_vector_type(4)));
typedef short s16x8 __attribute__((ext_vector_type(8)));
typedef short s16x4 __attribute__((ext_vector_type(4)));
using u16 = unsigned short;

__device__ __forceinline__ u16 f2bf(float f) {
  unsigned int u = __float_as_uint(f);
  u += 0x7fffu + ((u >> 16) & 1u);   // RNE
  return (u16)(u >> 16);
}
__device__ __forceinline__ float bf2f(u16 h) {
  return __uint_as_float(((unsigned int)h) << 16);
}
// involution swizzle within a slot ([rows][32 bf16] = row*64B); row-pair-local.
__device__ __forceinline__ int swz16k(int off) {
  return off ^ (((off >> 7) & 3) << 4);
}

// ------------------- fused weight transpose+cast AND x cast ----------------
__global__ __launch_bounds__(256) void cvt_all_kern(const float* __restrict__ x,
                                                    const float* __restrict__ W0,
                                                    const float* __restrict__ W1,
                                                    const float* __restrict__ W2,
                                                    const float* __restrict__ W3,
                                                    u16* __restrict__ WT,
                                                    u16* __restrict__ xb) {
  __shared__ float tile[64][65];
  const int tid = threadIdx.x;
  if (blockIdx.x < 1024) {
    const int blk = blockIdx.x & 255;
    const int sel = blockIdx.x >> 8;
    const float* W = (sel == 0) ? W0 : (sel == 1) ? W1 : (sel == 2) ? W2 : W3;
    u16* dst = WT + (size_t)sel * DIMN * DIMN;
    const int k0 = (blk >> 4) << 6;
    const int n0 = (blk & 15) << 6;
    const int r = tid >> 6;
    const int c = tid & 63;
#pragma unroll
    for (int i = 0; i < 16; ++i) {
      int row = (i << 2) + r;
      tile[row][c] = W[(size_t)(k0 + row) * DIMN + n0 + c];
    }
    __syncthreads();
#pragma unroll
    for (int i = 0; i < 16; ++i) {
      int row = (i << 2) + r;
      dst[(size_t)(n0 + row) * DIMN + k0 + c] = f2bf(tile[c][row]);
    }
  } else {
    size_t i = ((size_t)(blockIdx.x - 1024) * 256 + tid) * 4;
    f32x4 v = *(const f32x4*)(x + i);
    s16x4 o;
    o.x = (short)f2bf(v.x); o.y = (short)f2bf(v.y);
    o.z = (short)f2bf(v.z); o.w = (short)f2bf(v.w);
    *(s16x4*)(xb + i) = o;
  }
}

// ------------- QKV: 128x256 triple-buffered counted-vmcnt bf16 GEMM ---------
// (R14 verified — frozen)
__global__ __launch_bounds__(512, 4) void gemm_qkv(
    const u16* __restrict__ A, const u16* __restrict__ Bt,
    u16* __restrict__ dq, u16* __restrict__ dk, u16* __restrict__ dv) {
  constexpr int K = 1024;
  constexpr int BNT = 12;                     // N / 256
  constexpr int NT = K / 32;                  // 32 K-steps
  __shared__ char lds[73728];                 // 3 x 24576; reused by epilogue

  const int tid = threadIdx.x;
  const int l = tid & 63;
  const int w = tid >> 6;
  const int wm = w >> 2;
  const int wn = w & 3;

  const int xcd = (int)blockIdx.x & 7;
  const int idx = (int)blockIdx.x >> 3;
  const int g = idx / (4 * BNT);
  const int r2 = idx % (4 * BNT);
  const int bn = r2 >> 2;
  const int bm = xcd * 16 + g * 4 + (r2 & 3);
  const size_t arow0 = (size_t)bm * 128;
  const size_t brow0 = (size_t)bn * 256;

  int lrow[2], lcol[2];
#pragma unroll
  for (int i = 0; i < 2; ++i) {
    int lg2 = swz16k((i * 512 + tid) * 16);
    lrow[i] = lg2 >> 6;
    lcol[i] = (lg2 & 63) >> 1;
  }

  const int fr = l & 15;
  const int kswz = (((l >> 4) << 4)) ^ ((((fr >> 1) & 3)) << 4);

  auto STAGE = [&](int buf, int matsel, int tt) {
    const int kbase = (tt & (NT - 1)) * 32;
#pragma unroll
    for (int i = 0; i < 2; ++i) {
      if (matsel == 0 && i == 1) break;
      const u16* src = (matsel == 0)
          ? A  + (arow0 + (size_t)lrow[i]) * K + kbase + lcol[i]
          : Bt + (brow0 + (size_t)lrow[i]) * K + kbase + lcol[i];
      char* dst = lds + (buf * 24576 + matsel * 8192 + (i * 512 + tid) * 16);
      __builtin_amdgcn_global_load_lds(
          (__attribute__((address_space(1))) const void*)src,
          (__attribute__((address_space(3))) void*)dst, 16, 0, 0);
    }
  };
  auto LDA = [&](int buf, int rowb) -> s16x8 {
    return *(const s16x8*)(lds + buf * 24576 + rowb * 64 + kswz);
  };
  auto LDB = [&](int buf, int rowb) -> s16x8 {
    return *(const s16x8*)(lds + buf * 24576 + 8192 + rowb * 64 + kswz);
  };

  f32x4 acc[4][4];
#pragma unroll
  for (int i = 0; i < 4; ++i)
#pragma unroll
    for (int j = 0; j < 4; ++j) acc[i][j] = {0.f, 0.f, 0.f, 0.f};

  STAGE(0, 0, 0); STAGE(0, 1, 0);
  STAGE(1, 0, 1); STAGE(1, 1, 1);
  asm volatile("s_waitcnt vmcnt(3)" ::: "memory");
  __builtin_amdgcn_sched_barrier(0);
  __builtin_amdgcn_s_barrier();

  const int amb = wm * 64;
  const int bnb = wn * 64;
  s16x8 af[4], bf[4];

  int bufR = 0, bufW = 2;
#pragma unroll 1
  for (int t = 0; t < NT; ++t) {
    STAGE(bufW, 0, t + 2);
    STAGE(bufW, 1, t + 2);
#pragma unroll
    for (int i = 0; i < 4; ++i) af[i] = LDA(bufR, amb + i * 16 + fr);
#pragma unroll
    for (int i = 0; i < 4; ++i) bf[i] = LDB(bufR, bnb + i * 16 + fr);
    __builtin_amdgcn_s_setprio(1);
#pragma unroll
    for (int mi = 0; mi < 4; ++mi)
#pragma unroll
      for (int ni = 0; ni < 4; ++ni)
        acc[mi][ni] = __builtin_amdgcn_mfma_f32_16x16x32_bf16(
            af[mi], bf[ni], acc[mi][ni], 0, 0, 0);
    __builtin_amdgcn_s_setprio(0);
    asm volatile("s_waitcnt vmcnt(3)" ::: "memory");
    __builtin_amdgcn_sched_barrier(0);
    __builtin_amdgcn_s_barrier();
    bufR = (bufR == 2) ? 0 : bufR + 1;
    bufW = (bufW == 2) ? 0 : bufW + 1;
  }

  asm volatile("s_waitcnt vmcnt(0) lgkmcnt(0)" ::: "memory");
  __builtin_amdgcn_sched_barrier(0);
  __builtin_amdgcn_s_barrier();

  const int r0 = (l >> 4) << 2;
  const int c0 = l & 15;
  const int mat = bn >> 2;                        // 0=q 1=k 2=v
  if (mat == 0) {
    u16* dst = dq;
    const size_t colbase = (size_t)(bn & 3) * 256 + (size_t)wn * 64;
#pragma unroll
    for (int mi = 0; mi < 4; ++mi) {
#pragma unroll
      for (int j = 0; j < 4; ++j) {
        float v0 = acc[mi][0][j], v1 = acc[mi][1][j];
        float v2 = acc[mi][2][j], v3 = acc[mi][3][j];
        float m = fmaxf(fmaxf(v0, v1), fmaxf(v2, v3));
#pragma unroll
        for (int off = 1; off < 16; off <<= 1) m = fmaxf(m, __shfl_xor(m, off));
        float e0 = __expf(v0 - m), e1 = __expf(v1 - m);
        float e2 = __expf(v2 - m), e3 = __expf(v3 - m);
        float s = e0 + e1 + e2 + e3;
#pragma unroll
        for (int off = 1; off < 16; off <<= 1) s += __shfl_xor(s, off);
        float inv = 1.f / s;
        const size_t row = arow0 + wm * 64 + mi * 16 + r0 + j;
        u16* p = dst + row * DIMN + colbase + c0;
        p[0]  = f2bf(e0 * inv); p[16] = f2bf(e1 * inv);
        p[32] = f2bf(e2 * inv); p[48] = f2bf(e3 * inv);
      }
    }
  } else {
    u16* dst = (mat == 1) ? dk : dv;
    u16* lt = (u16*)lds;
#pragma unroll
    for (int mi = 0; mi < 4; ++mi) {
      const int tl = wm * 64 + mi * 16 + r0;
#pragma unroll
      for (int ni = 0; ni < 4; ++ni) {
        const int cl = wn * 64 + ni * 16 + c0;
        s16x4 o;
#pragma unroll
        for (int j = 0; j < 4; ++j) {
          float v = acc[mi][ni][j];
          float r = (mat == 1) ? (v > 0.f ? v + 1.f : __expf(v)) : v;
          o[j] = (short)f2bf(r);
        }
        *(s16x4*)&lt[cl * 132 + tl] = o;
      }
    }
    __builtin_amdgcn_s_barrier();
    const int colb = (bn & 3) * 256;
    const int bb = (int)(arow0 >> 12);
    const int t0 = (int)(arow0 & 4095);
#pragma unroll
    for (int i = 0; i < 8; ++i) {
      const int chunk = i * 512 + tid;          // 4096 chunks
      const int cl = chunk >> 4;                // 0..255
      const int toct = (chunk & 15) * 8;
      s16x8 vv = *(const s16x8*)&lt[cl * 132 + toct];
      const int col = colb + cl;
      const int h = col >> 6, d = col & 63;
      *(s16x8*)&dst[((size_t)((bb * 16 + h) * 64 + d)) * 4096 + t0 + toct] = vv;
    }
  }
}

// ------------- OUT: 128x512 triple-buffered counted-vmcnt bf16 GEMM ---------
// (R14 — frozen)
__global__ __launch_bounds__(512, 2) void gemm_o(
    const u16* __restrict__ A, const u16* __restrict__ Bt,
    float* __restrict__ dO, const float* __restrict__ bias) {
  constexpr int K = 1024;
  constexpr int NT = K / 32;                  // 32 K-steps
  extern __shared__ char lds[];               // 3 x 40960

  const int tid = threadIdx.x;
  const int l = tid & 63;
  const int w = tid >> 6;
  const int wm = w >> 2;
  const int wn = w & 3;

  const int xcd = (int)blockIdx.x & 7;
  const int idx = (int)blockIdx.x >> 3;       // 0..31
  const int bm = xcd * 16 + (idx & 15);       // 0..127
  const int bn = idx >> 4;                    // 0..1
  const size_t arow0 = (size_t)bm * 128;
  const size_t brow0 = (size_t)bn * 512;

  int lrowA, lcolA, lrowB[4], lcolB[4];
  {
    int lg2 = swz16k(tid * 16);
    lrowA = lg2 >> 6; lcolA = (lg2 & 63) >> 1;
#pragma unroll
    for (int i = 0; i < 4; ++i) {
      int lb = swz16k((i * 512 + tid) * 16);
      lrowB[i] = lb >> 6; lcolB[i] = (lb & 63) >> 1;
    }
  }

  const int fr = l & 15;
  const int kswz = (((l >> 4) << 4)) ^ ((((fr >> 1) & 3)) << 4);

  auto STAGE = [&](int buf, int tt) {
    const int kbase = (tt & (NT - 1)) * 32;
    {
      const u16* src = A + (arow0 + (size_t)lrowA) * K + kbase + lcolA;
      char* dst = lds + (buf * 40960 + tid * 16);
      __builtin_amdgcn_global_load_lds(
          (__attribute__((address_space(1))) const void*)src,
          (__attribute__((address_space(3))) void*)dst, 16, 0, 0);
    }
#pragma unroll
    for (int i = 0; i < 4; ++i) {
      const u16* src = Bt + (brow0 + (size_t)lrowB[i]) * K + kbase + lcolB[i];
      char* dst = lds + (buf * 40960 + 8192 + (i * 512 + tid) * 16);
      __builtin_amdgcn_global_load_lds(
          (__attribute__((address_space(1))) const void*)src,
          (__attribute__((address_space(3))) void*)dst, 16, 0, 0);
    }
  };
  auto LDA = [&](int buf, int rowb) -> s16x8 {
    return *(const s16x8*)(lds + buf * 40960 + rowb * 64 + kswz);
  };
  auto LDB = [&](int buf, int rowb) -> s16x8 {
    return *(const s16x8*)(lds + buf * 40960 + 8192 + rowb * 64 + kswz);
  };

  f32x4 acc[4][8];
#pragma unroll
  for (int i = 0; i < 4; ++i)
#pragma unroll
    for (int j = 0; j < 8; ++j) acc[i][j] = {0.f, 0.f, 0.f, 0.f};

  STAGE(0, 0);
  STAGE(1, 1);
  asm volatile("s_waitcnt vmcnt(5)" ::: "memory");
  __builtin_amdgcn_sched_barrier(0);
  __builtin_amdgcn_s_barrier();

  const int amb = wm * 64;
  const int bnb = wn * 128;
  s16x8 af[4], bf[8];

  int bufR = 0, bufW = 2;
#pragma unroll 1
  for (int t = 0; t < NT; ++t) {
    STAGE(bufW, t + 2);
#pragma unroll
    for (int i = 0; i < 4; ++i) af[i] = LDA(bufR, amb + i * 16 + fr);
#pragma unroll
    for (int i = 0; i < 8; ++i) bf[i] = LDB(bufR, bnb + i * 16 + fr);
    __builtin_amdgcn_s_setprio(1);
#pragma unroll
    for (int mi = 0; mi < 4; ++mi)
#pragma unroll
      for (int ni = 0; ni < 8; ++ni)
        acc[mi][ni] = __builtin_amdgcn_mfma_f32_16x16x32_bf16(
            af[mi], bf[ni], acc[mi][ni], 0, 0, 0);
    __builtin_amdgcn_s_setprio(0);
    asm volatile("s_waitcnt vmcnt(5)" ::: "memory");
    __builtin_amdgcn_sched_barrier(0);
    __builtin_amdgcn_s_barrier();
    bufR = (bufR == 2) ? 0 : bufR + 1;
    bufW = (bufW == 2) ? 0 : bufW + 1;
  }

  const int r0 = (l >> 4) << 2;
  const int c0 = l & 15;
#pragma unroll
  for (int mi = 0; mi < 4; ++mi)
#pragma unroll
    for (int ni = 0; ni < 8; ++ni) {
      const size_t col = brow0 + (size_t)wn * 128 + ni * 16 + c0;
      const float bv = bias[col];
#pragma unroll
      for (int j = 0; j < 4; ++j) {
        const size_t row = arow0 + wm * 64 + mi * 16 + r0 + j;
        dO[row * DIMN + col] = acc[mi][ni][j] + bv;
      }
    }
}

// ------------- fused middle v4: 4 buckets/iter, 8-buffer ring ---------------
// Block = (bh, eg), 512 thr = 8 waves (4 ctx + 4 attn).  Iteration t handles
// buckets 4t..4t+3: ctx publishes C_prev into bufs (4t+s)&7 then accumulates;
// attn one iteration behind reads bufs (4(t-1)+s)&7 (disjoint mod 8).
// ONE barrier per 4 buckets (33 -> 17).  Loop t=0..16; ctx active t<16,
// attn active t>=1 (wave-uniform guards; barrier outside guards).
__global__ __launch_bounds__(512) void mid_fused_kern(const u16* __restrict__ kT,
                                                      const u16* __restrict__ vT,
                                                      const u16* __restrict__ qb,
                                                      u16* __restrict__ attn) {
  __shared__ u16 cprev[8][16][72];   // bf16 [e][d], 144B rows
  const int tid = threadIdx.x;
  const int l = tid & 63;
  const int w = tid >> 6;           // 0..7
  const int ws = w & 3;
  const bool isCtx = w < 4;
  const int fr = l & 15;
  const int lg = l >> 4;            // 0..3

  const int bid = (int)blockIdx.x;
  const int xcd = bid & 7;
  const int slot = bid >> 3;        // 0..31
  const int bh = xcd * 8 + (slot >> 2);
  const int eg = slot & 3;
  const int b = bh >> 4, h = bh & 15;

  const size_t kvbase = (size_t)bh * 64 * 4096;   // [d][t]
  const size_t qrow0 = (size_t)b * T_LEN;

  if (isCtx) {
    auto LV = [&](int u, int kk) -> s16x8 {   // vT rows e (A operand)
      return *(const s16x8*)&vT[kvbase + (size_t)(eg * 16 + fr) * 4096 +
                                u * 64 + kk * 32 + lg * 8];
    };
    auto LK = [&](int u, int kk) -> s16x8 {   // kT rows d (B operand)
      return *(const s16x8*)&kT[kvbase + (size_t)(ws * 16 + fr) * 4096 +
                                u * 64 + kk * 32 + lg * 8];
    };
    f32x4 cacc = {0.f, 0.f, 0.f, 0.f};   // rows e=lg*4+j, col d=ws*16+fr
    float ksum = 0.f;
    s16x8 vA[4][2], kB[4][2];
#pragma unroll
    for (int s = 0; s < 4; ++s)
#pragma unroll
      for (int kk = 0; kk < 2; ++kk) {
        vA[s][kk] = LV(s, kk);
        kB[s][kk] = LK(s, kk);
      }
#pragma unroll 1
    for (int t = 0; t <= 16; ++t) {
      if (t < 16) {
        s16x8 a[4][2], b2[4][2];
#pragma unroll
        for (int s = 0; s < 4; ++s)
#pragma unroll
          for (int kk = 0; kk < 2; ++kk) {
            a[s][kk] = vA[s][kk];
            b2[s][kk] = kB[s][kk];
          }
        if (t < 15) {
#pragma unroll
          for (int s = 0; s < 4; ++s)
#pragma unroll
            for (int kk = 0; kk < 2; ++kk) {
              vA[s][kk] = LV(4 * t + 4 + s, kk);
              kB[s][kk] = LK(4 * t + 4 + s, kk);
            }
        }
#pragma unroll
        for (int s = 0; s < 4; ++s) {
          // publish C through bucket 4t+s-1, then accumulate S_{4t+s}
          const float inv = 1.f / (ksum + 1e-6f);
          u16* pp = &cprev[(4 * t + s) & 7][lg * 4][ws * 16 + fr];
#pragma unroll
          for (int j = 0; j < 4; ++j) pp[j * 72] = f2bf(cacc[j] * inv);
          cacc = __builtin_amdgcn_mfma_f32_16x16x32_bf16(a[s][0], b2[s][0],
                                                         cacc, 0, 0, 0);
          cacc = __builtin_amdgcn_mfma_f32_16x16x32_bf16(a[s][1], b2[s][1],
                                                         cacc, 0, 0, 0);
          float ss = 0.f;
#pragma unroll
          for (int j = 0; j < 8; ++j)
            ss += bf2f((u16)b2[s][0][j]) + bf2f((u16)b2[s][1][j]);
          ss += __shfl_xor(ss, 16);
          ss += __shfl_xor(ss, 32);
          ksum += ss;
        }
      }
      __syncthreads();
    }
  } else {
    auto LQ = [&](int u, int kk) -> s16x8 {   // q rows n (A operand)
      return *(const s16x8*)&qb[(qrow0 + u * 64 + ws * 16 + fr) * DIMN +
                                (size_t)h * 64 + kk * 32 + lg * 8];
    };
    s16x8 qA[4][2];
#pragma unroll
    for (int s = 0; s < 4; ++s)
#pragma unroll
      for (int kk = 0; kk < 2; ++kk) qA[s][kk] = LQ(s, kk);
#pragma unroll 1
    for (int t = 0; t <= 16; ++t) {
      if (t >= 1) {
        s16x8 c[4][2];
#pragma unroll
        for (int s = 0; s < 4; ++s)
#pragma unroll
          for (int kk = 0; kk < 2; ++kk) c[s][kk] = qA[s][kk];
        if (t < 16) {
#pragma unroll
          for (int s = 0; s < 4; ++s)
#pragma unroll
            for (int kk = 0; kk < 2; ++kk) qA[s][kk] = LQ(4 * t + s, kk);
        }
#pragma unroll
        for (int s = 0; s < 4; ++s) {
          const int u = 4 * (t - 1) + s;
          s16x8 cB0 = *(const s16x8*)&cprev[u & 7][fr][lg * 8];
          s16x8 cB1 = *(const s16x8*)&cprev[u & 7][fr][32 + lg * 8];
          f32x4 aacc = {0.f, 0.f, 0.f, 0.f};
          aacc = __builtin_amdgcn_mfma_f32_16x16x32_bf16(c[s][0], cB0, aacc,
                                                         0, 0, 0);
          aacc = __builtin_amdgcn_mfma_f32_16x16x32_bf16(c[s][1], cB1, aacc,
                                                         0, 0, 0);
          const size_t arow = qrow0 + (size_t)u * 64 + ws * 16 + lg * 4;
#pragma unroll
          for (int j = 0; j < 4; ++j)
            attn[(arow + j) * DIMN + (size_t)h * 64 + eg * 16 + fr] =
                f2bf(aacc[j]);
        }
      }
      __syncthreads();
    }
  }
}

// ---------------------------------------------------------------------------
extern "C" void kernel_launch(void* const* d_in, const int* in_sizes, int n_in,
                              void* d_out, int out_size, void* d_ws, size_t ws_size,
                              hipStream_t stream) {
  const float* x  = (const float*)d_in[0];
  const float* Wq = (const float*)d_in[1];
  const float* Wk = (const float*)d_in[2];
  const float* Wv = (const float*)d_in[3];
  const float* Wo = (const float*)d_in[4];
  const float* bo = (const float*)d_in[5];
  float* out = (float*)d_out;

  constexpr size_t SZ_XB = (size_t)MROWS * DIMN * 2;
  constexpr size_t SZ_WT = (size_t)DIMN * DIMN * 2;
  char* ws = (char*)d_ws;
  u16*   xb   = (u16*)(ws);
  u16*   wqT  = (u16*)(ws + SZ_XB);          // wq/wk/wv/wo contiguous
  u16*   woT  = (u16*)(ws + SZ_XB + 3 * SZ_WT);
  u16*   qb   = (u16*)(ws + SZ_XB + 4 * SZ_WT);
  u16*   kT   = (u16*)(ws + 2 * SZ_XB + 4 * SZ_WT);   // [bh][d][t]
  u16*   vT   = (u16*)(ws + 3 * SZ_XB + 4 * SZ_WT);   // [bh][d][t]
  u16*   attn = xb;  // xb dead after QKV GEMM

  (void)hipFuncSetAttribute((const void*)gemm_o,
                            hipFuncAttributeMaxDynamicSharedMemorySize, 122880);

  cvt_all_kern<<<1024 + MROWS * DIMN / 1024, 256, 0, stream>>>(x, Wq, Wk, Wv, Wo,
                                                               wqT, xb);

  // fused QKV: N = 3072, grid 128 x 12 = 1536
  gemm_qkv<<<1536, 512, 0, stream>>>(xb, wqT, qb, kT, vT);

  // fused middle: ctx + cumnorm + attn, 4 buckets/iter, 8-buffer ring
  mid_fused_kern<<<256, 512, 0, stream>>>(kT, vT, qb, attn);

  // output: N = 1024, grid 128 x 2 = 256, BN=512
  gemm_o<<<256, 512, 122880, stream>>>(attn, woT, out, bo);
}